// Round 3
// baseline (750.122 us; speedup 1.0000x reference)
//
#include <hip/hip_runtime.h>
#include <cstdint>
#include <cstddef>

typedef short short8 __attribute__((ext_vector_type(8)));
typedef float f32x4 __attribute__((ext_vector_type(4)));

#define DIN  4096
#define DOUT 4096
#define RANK 64
#define NEXP 16
#define NTOK 8192
#define KCAT 5120   // DIN + NEXP*RANK

// ---------- helpers ----------
__device__ __forceinline__ unsigned short f2bf(float f) {
    unsigned int u = __builtin_bit_cast(unsigned int, f);
    u = (u + 0x7FFFu + ((u >> 16) & 1u)) >> 16;   // RNE
    return (unsigned short)u;
}
__device__ __forceinline__ void async_cp16(const void* g, void* lds) {
    __builtin_amdgcn_global_load_lds(
        (const __attribute__((address_space(1))) void*)g,
        (__attribute__((address_space(3))) void*)lds, 16, 0, 0);
}

// ---------- kernel 1: all conversion + fp32 router logits ----------
// blocks [0,1024):  x -> Xcat bf16 hi  +  Lg[t][e] = sum_k x[t][k]*rw[e][k] (fp32)
// blocks [1024,3072): base_w|B -> Wcat bf16,  A -> W1A bf16
__global__ void __launch_bounds__(256) prep_all_kernel(
        const float* __restrict__ x, const float* __restrict__ rw,
        const float* __restrict__ bw, const float* __restrict__ Bm,
        const float* __restrict__ Am,
        unsigned short* __restrict__ Xcat, unsigned short* __restrict__ Wcat,
        unsigned short* __restrict__ W1A, float* __restrict__ Lg) {
    __shared__ __align__(16) float xsl[8][532];     // stashed x window (padded rows)
    __shared__ __align__(16) float red[8][16][16];  // [t][e][c]
    const int tid = threadIdx.x;

    if (blockIdx.x < 1024) {
        // ---- part A: token conversion + logits ----
        const int t0 = blockIdx.x * 8;
        const int tt = tid >> 5, l32 = tid & 31;
        const int eg = tid >> 6, ts = (tid >> 4) & 3, cc = tid & 15;
        float part[2][4] = {};

        for (int w = 0; w < 8; ++w) {
            #pragma unroll
            for (int sub = 0; sub < 4; ++sub) {
                const int col = w * 512 + sub * 128 + l32 * 4;
                const float4 xv = *(const float4*)&x[(size_t)(t0 + tt) * DIN + col];
                unsigned short b0 = f2bf(xv.x), b1 = f2bf(xv.y),
                               b2 = f2bf(xv.z), b3 = f2bf(xv.w);
                uint2 pk = { (unsigned)b0 | ((unsigned)b1 << 16),
                             (unsigned)b2 | ((unsigned)b3 << 16) };
                *(uint2*)&Xcat[(size_t)(t0 + tt) * KCAT + col] = pk;
                *(float4*)&xsl[tt][sub * 128 + l32 * 4] = xv;
            }
            __syncthreads();
            #pragma unroll
            for (int j = 0; j < 8; ++j) {
                const int colb = w * 512 + (j * 16 + cc) * 4;
                const float4 r0 = *(const float4*)&rw[(size_t)(eg * 4 + 0) * DIN + colb];
                const float4 r1 = *(const float4*)&rw[(size_t)(eg * 4 + 1) * DIN + colb];
                const float4 r2 = *(const float4*)&rw[(size_t)(eg * 4 + 2) * DIN + colb];
                const float4 r3 = *(const float4*)&rw[(size_t)(eg * 4 + 3) * DIN + colb];
                #pragma unroll
                for (int t2 = 0; t2 < 2; ++t2) {
                    const int t = ts * 2 + t2;
                    const float4 xv = *(const float4*)&xsl[t][(j * 16 + cc) * 4];
                    part[t2][0] += xv.x * r0.x + xv.y * r0.y + xv.z * r0.z + xv.w * r0.w;
                    part[t2][1] += xv.x * r1.x + xv.y * r1.y + xv.z * r1.z + xv.w * r1.w;
                    part[t2][2] += xv.x * r2.x + xv.y * r2.y + xv.z * r2.z + xv.w * r2.w;
                    part[t2][3] += xv.x * r3.x + xv.y * r3.y + xv.z * r3.z + xv.w * r3.w;
                }
            }
            __syncthreads();
        }
        #pragma unroll
        for (int t2 = 0; t2 < 2; ++t2)
            #pragma unroll
            for (int e = 0; e < 4; ++e)
                red[ts * 2 + t2][eg * 4 + e][cc] = part[t2][e];
        __syncthreads();
        if (tid < 128) {
            const int t = tid >> 4, e = tid & 15;
            float s = 0.f;
            #pragma unroll
            for (int c = 0; c < 16; ++c) s += red[t][e][c];
            Lg[(size_t)(t0 + t) * NEXP + e] = s;
        }
    } else {
        // ---- part B: weight conversion (grid-stride) ----
        const unsigned NG1 = (unsigned)DOUT * KCAT / 8u;       // 2,621,440
        const unsigned NGT = NG1 + 64u * DIN / 8u;             // + 32,768
        for (unsigned g = (blockIdx.x - 1024) * 256u + tid; g < NGT;
             g += 2048u * 256u) {
            const float* src;
            unsigned short* dst;
            if (g < NG1) {
                unsigned o  = g / 640u;
                unsigned c8 = (g - o * 640u) * 8u;
                dst = Wcat + (size_t)o * KCAT + c8;
                if (c8 < DIN) {
                    src = bw + (size_t)o * DIN + c8;
                } else {
                    unsigned cc2 = c8 - DIN;
                    unsigned e = cc2 >> 6, r = cc2 & 63u;
                    src = Bm + ((size_t)e * DOUT + o) * RANK + r;
                }
            } else {
                unsigned g2 = g - NG1;
                unsigned row = g2 >> 9;
                unsigned c8  = (g2 & 511u) * 8u;
                dst = W1A + (size_t)row * DIN + c8;
                src = Am + (size_t)row * DIN + c8;
            }
            float4 v0 = *(const float4*)(src);
            float4 v1 = *(const float4*)(src + 4);
            uint4 pk;
            pk.x = (unsigned)f2bf(v0.x) | ((unsigned)f2bf(v0.y) << 16);
            pk.y = (unsigned)f2bf(v0.z) | ((unsigned)f2bf(v0.w) << 16);
            pk.z = (unsigned)f2bf(v1.x) | ((unsigned)f2bf(v1.y) << 16);
            pk.w = (unsigned)f2bf(v1.z) | ((unsigned)f2bf(v1.w) << 16);
            *(uint4*)dst = pk;
        }
    }
}

// ---------- kernel 2: h = Xhi @ A^T (MFMA), fused softmax/top2 -> H16 ----------
// 32 tokens/block, full K, no split-K, no atomics.  H16 written into Xcat cols 4096..5120.
__global__ void __launch_bounds__(256) proj_moe_kernel(
        const unsigned short* __restrict__ Xcat,
        const unsigned short* __restrict__ W1A,
        const float* __restrict__ Lg, unsigned short* __restrict__ XcatW) {
    __shared__ __align__(16) unsigned short Xs[32 * 64];   // 4 KB
    __shared__ __align__(16) unsigned short Ws[64 * 64];   // 8 KB
    __shared__ __align__(16) float cw[32][16];             // combine wts * 0.5
    __shared__ __align__(16) float hbuf[32][68];           // h round-trip
    const int tid = threadIdx.x;
    const int wave = tid >> 6, lane = tid & 63;
    const int quad = lane >> 4, l16 = lane & 15;
    const int t0 = blockIdx.x * 32;
    const int srow = tid >> 3;
    const int scol = ((tid & 7) ^ (srow & 7)) * 8;

    // per-token routing coefficients (independent of K-loop)
    if (tid < 32) {
        float l[16];
        #pragma unroll
        for (int e = 0; e < 16; ++e) l[e] = Lg[(size_t)(t0 + tid) * NEXP + e];
        int i1 = 0; float b1v = l[0];
        #pragma unroll
        for (int e = 1; e < 16; ++e) if (l[e] > b1v) { b1v = l[e]; i1 = e; }
        int i2 = -1; float b2v = -1e30f;
        #pragma unroll
        for (int e = 0; e < 16; ++e) if (e != i1 && l[e] > b2v) { b2v = l[e]; i2 = e; }
        float S = 0.f;
        #pragma unroll
        for (int e = 0; e < 16; ++e) S += expf(l[e] - b1v);
        const float p1 = 1.0f / S;
        const float p2 = expf(b2v - b1v) / S;
        const float d = p1 + p2 + 1e-6f;
        const float c1 = 0.5f * p1 / d;   // SCALING=0.5 folded
        const float c2 = 0.5f * p2 / d;
        #pragma unroll
        for (int e = 0; e < 16; ++e)
            cw[tid][e] = (e == i1) ? c1 : (e == i2) ? c2 : 0.0f;
    }

    f32x4 acc[2] = {};
    for (int kt = 0; kt < DIN / 64; ++kt) {
        const int k0 = kt * 64;
        async_cp16(Xcat + (size_t)(t0 + srow) * KCAT + k0 + scol,
                   (char*)Xs + wave * 1024);
        #pragma unroll
        for (int i = 0; i < 2; ++i)
            async_cp16(W1A + (size_t)(i * 32 + srow) * DIN + k0 + scol,
                       (char*)Ws + i * 4096 + wave * 1024);
        __syncthreads();
        #pragma unroll
        for (int kk = 0; kk < 2; ++kk) {
            const int cs = ((kk * 4 + quad) ^ (l16 & 7)) << 3;
            short8 bn = *(const short8*)&Ws[(wave * 16 + l16) * 64 + cs];
            #pragma unroll
            for (int i = 0; i < 2; ++i) {
                short8 am = *(const short8*)&Xs[(i * 16 + l16) * 64 + cs];
                acc[i] = __builtin_amdgcn_mfma_f32_16x16x32_bf16(am, bn, acc[i], 0, 0, 0);
            }
        }
        __syncthreads();
    }
    // stash h: row = token-in-block, col = rank
    #pragma unroll
    for (int i = 0; i < 2; ++i)
        #pragma unroll
        for (int r = 0; r < 4; ++r)
            hbuf[i * 16 + quad * 4 + r][wave * 16 + l16] = acc[i][r];
    __syncthreads();
    // H16 write: thread = (token t, part): experts {2*part, 2*part+1}
    const int t = tid >> 3, part = tid & 7;
    unsigned short* dst = XcatW + (size_t)(t0 + t) * KCAT + DIN;
    #pragma unroll
    for (int ee = 0; ee < 2; ++ee) {
        const int e = part * 2 + ee;
        const float c = cw[t][e];
        #pragma unroll
        for (int r8 = 0; r8 < 8; ++r8) {
            uint4 pk;
            unsigned short o16[8];
            #pragma unroll
            for (int k = 0; k < 8; ++k)
                o16[k] = f2bf(c * hbuf[t][r8 * 8 + k]);
            pk.x = (unsigned)o16[0] | ((unsigned)o16[1] << 16);
            pk.y = (unsigned)o16[2] | ((unsigned)o16[3] << 16);
            pk.z = (unsigned)o16[4] | ((unsigned)o16[5] << 16);
            pk.w = (unsigned)o16[6] | ((unsigned)o16[7] << 16);
            *(uint4*)(dst + e * 64 + r8 * 8) = pk;
        }
    }
}

// ---------- kernel 3: out = Xcat @ Wcat^T + bias  (M=8192,N=4096,K=5120) ----------
__global__ void __launch_bounds__(256) gemm_main_kernel(
        const unsigned short* __restrict__ Xcat,
        const unsigned short* __restrict__ Wcat,
        const float* __restrict__ bias, float* __restrict__ out) {
    __shared__ __align__(16) unsigned short Xs[128 * 64];
    __shared__ __align__(16) unsigned short Ws[128 * 64];
    const int tid = threadIdx.x;
    const int wave = tid >> 6, lane = tid & 63;
    const int quad = lane >> 4, l16 = lane & 15;
    const int bn0 = blockIdx.x * 128;
    const int bm0 = blockIdx.y * 128;
    const int srow = tid >> 3;
    const int scol = ((tid & 7) ^ (srow & 7)) * 8;
    const unsigned short* gx = Xcat + (size_t)(bm0 + srow) * KCAT + scol;
    const unsigned short* gw = Wcat + (size_t)(bn0 + srow) * KCAT + scol;
    const int wm0 = (wave & 1) * 64;
    const int wn0 = (wave >> 1) * 64;
    f32x4 acc[4][4] = {};
    for (int kt = 0; kt < KCAT / 64; ++kt) {
        const int k0 = kt * 64;
        #pragma unroll
        for (int i = 0; i < 4; ++i) {
            async_cp16(gx + (size_t)(i * 32) * KCAT + k0, (char*)Xs + i * 4096 + wave * 1024);
            async_cp16(gw + (size_t)(i * 32) * KCAT + k0, (char*)Ws + i * 4096 + wave * 1024);
        }
        __syncthreads();
        #pragma unroll
        for (int kk = 0; kk < 2; ++kk) {
            short8 am[4], bn[4];
            #pragma unroll
            for (int i = 0; i < 4; ++i)
                am[i] = *(const short8*)&Xs[(wm0 + i * 16 + l16) * 64 +
                                            (((kk * 4 + quad) ^ (l16 & 7)) << 3)];
            #pragma unroll
            for (int j = 0; j < 4; ++j)
                bn[j] = *(const short8*)&Ws[(wn0 + j * 16 + l16) * 64 +
                                            (((kk * 4 + quad) ^ (l16 & 7)) << 3)];
            #pragma unroll
            for (int i = 0; i < 4; ++i)
                #pragma unroll
                for (int j = 0; j < 4; ++j)
                    acc[i][j] = __builtin_amdgcn_mfma_f32_16x16x32_bf16(
                        am[i], bn[j], acc[i][j], 0, 0, 0);
        }
        __syncthreads();
    }
    #pragma unroll
    for (int j = 0; j < 4; ++j) {
        const int col = bn0 + wn0 + j * 16 + l16;
        const float bj = bias[col];
        #pragma unroll
        for (int i = 0; i < 4; ++i) {
            const int row0 = bm0 + wm0 + i * 16 + quad * 4;
            #pragma unroll
            for (int r = 0; r < 4; ++r)
                out[(size_t)(row0 + r) * DOUT + col] = acc[i][j][r] + bj;
        }
    }
}

// ---------- host ----------
extern "C" void kernel_launch(void* const* d_in, const int* in_sizes, int n_in,
                              void* d_out, int out_size, void* d_ws, size_t ws_size,
                              hipStream_t stream) {
    const float* x  = (const float*)d_in[0];
    const float* bw = (const float*)d_in[1];
    const float* bb = (const float*)d_in[2];
    const float* Am = (const float*)d_in[3];
    const float* Bm = (const float*)d_in[4];
    const float* rw = (const float*)d_in[5];
    float* out = (float*)d_out;
    char* ws = (char*)d_ws;
    unsigned short* Xcat = (unsigned short*)(ws);                 // 8192*5120*2 = 83,886,080
    unsigned short* Wcat = (unsigned short*)(ws + 83886080);      // 4096*5120*2 = 41,943,040
    unsigned short* W1A  = (unsigned short*)(ws + 125829120);     // 64*4096*2   =    524,288
    float* Lg = (float*)(ws + 126353408);                         // 8192*16*4   =    524,288

    hipLaunchKernelGGL(prep_all_kernel, dim3(3072),   dim3(256), 0, stream,
                       x, rw, bw, Bm, Am, Xcat, Wcat, W1A, Lg);
    hipLaunchKernelGGL(proj_moe_kernel, dim3(256),    dim3(256), 0, stream,
                       Xcat, W1A, Lg, Xcat);
    hipLaunchKernelGGL(gemm_main_kernel, dim3(32, 64), dim3(256), 0, stream,
                       Xcat, Wcat, bb, out);
}

// Round 4
// 688.400 us; speedup vs baseline: 1.0897x; 1.0897x over previous
//
#include <hip/hip_runtime.h>
#include <cstdint>
#include <cstddef>

typedef short short8 __attribute__((ext_vector_type(8)));
typedef float f32x4 __attribute__((ext_vector_type(4)));
typedef float f32x16 __attribute__((ext_vector_type(16)));

#define DIN  4096
#define DOUT 4096
#define RANK 64
#define NEXP 16
#define NTOK 8192
#define KCAT 5120   // DIN + NEXP*RANK

// ---------- helpers ----------
__device__ __forceinline__ unsigned short f2bf(float f) {
    unsigned int u = __builtin_bit_cast(unsigned int, f);
    u = (u + 0x7FFFu + ((u >> 16) & 1u)) >> 16;   // RNE
    return (unsigned short)u;
}
__device__ __forceinline__ void async_cp16(const void* g, void* lds) {
    __builtin_amdgcn_global_load_lds(
        (const __attribute__((address_space(1))) void*)g,
        (__attribute__((address_space(3))) void*)lds, 16, 0, 0);
}

// ---------- kernel 1: all conversion + fp32 router logits ----------
__global__ void __launch_bounds__(256) prep_all_kernel(
        const float* __restrict__ x, const float* __restrict__ rw,
        const float* __restrict__ bw, const float* __restrict__ Bm,
        const float* __restrict__ Am,
        unsigned short* __restrict__ Xcat, unsigned short* __restrict__ Wcat,
        unsigned short* __restrict__ W1A, float* __restrict__ Lg) {
    __shared__ __align__(16) float xsl[8][532];
    __shared__ __align__(16) float red[8][16][16];
    const int tid = threadIdx.x;

    if (blockIdx.x < 1024) {
        const int t0 = blockIdx.x * 8;
        const int tt = tid >> 5, l32 = tid & 31;
        const int eg = tid >> 6, ts = (tid >> 4) & 3, cc = tid & 15;
        float part[2][4] = {};

        for (int w = 0; w < 8; ++w) {
            #pragma unroll
            for (int sub = 0; sub < 4; ++sub) {
                const int col = w * 512 + sub * 128 + l32 * 4;
                const float4 xv = *(const float4*)&x[(size_t)(t0 + tt) * DIN + col];
                unsigned short b0 = f2bf(xv.x), b1 = f2bf(xv.y),
                               b2 = f2bf(xv.z), b3 = f2bf(xv.w);
                uint2 pk = { (unsigned)b0 | ((unsigned)b1 << 16),
                             (unsigned)b2 | ((unsigned)b3 << 16) };
                *(uint2*)&Xcat[(size_t)(t0 + tt) * KCAT + col] = pk;
                *(float4*)&xsl[tt][sub * 128 + l32 * 4] = xv;
            }
            __syncthreads();
            #pragma unroll
            for (int j = 0; j < 8; ++j) {
                const int colb = w * 512 + (j * 16 + cc) * 4;
                const float4 r0 = *(const float4*)&rw[(size_t)(eg * 4 + 0) * DIN + colb];
                const float4 r1 = *(const float4*)&rw[(size_t)(eg * 4 + 1) * DIN + colb];
                const float4 r2 = *(const float4*)&rw[(size_t)(eg * 4 + 2) * DIN + colb];
                const float4 r3 = *(const float4*)&rw[(size_t)(eg * 4 + 3) * DIN + colb];
                #pragma unroll
                for (int t2 = 0; t2 < 2; ++t2) {
                    const int t = ts * 2 + t2;
                    const float4 xv = *(const float4*)&xsl[t][(j * 16 + cc) * 4];
                    part[t2][0] += xv.x * r0.x + xv.y * r0.y + xv.z * r0.z + xv.w * r0.w;
                    part[t2][1] += xv.x * r1.x + xv.y * r1.y + xv.z * r1.z + xv.w * r1.w;
                    part[t2][2] += xv.x * r2.x + xv.y * r2.y + xv.z * r2.z + xv.w * r2.w;
                    part[t2][3] += xv.x * r3.x + xv.y * r3.y + xv.z * r3.z + xv.w * r3.w;
                }
            }
            __syncthreads();
        }
        #pragma unroll
        for (int t2 = 0; t2 < 2; ++t2)
            #pragma unroll
            for (int e = 0; e < 4; ++e)
                red[ts * 2 + t2][eg * 4 + e][cc] = part[t2][e];
        __syncthreads();
        if (tid < 128) {
            const int t = tid >> 4, e = tid & 15;
            float s = 0.f;
            #pragma unroll
            for (int c = 0; c < 16; ++c) s += red[t][e][c];
            Lg[(size_t)(t0 + t) * NEXP + e] = s;
        }
    } else {
        const unsigned NG1 = (unsigned)DOUT * KCAT / 8u;       // 2,621,440
        const unsigned NGT = NG1 + 64u * DIN / 8u;             // + 32,768
        for (unsigned g = (blockIdx.x - 1024) * 256u + tid; g < NGT;
             g += 2048u * 256u) {
            const float* src;
            unsigned short* dst;
            if (g < NG1) {
                unsigned o  = g / 640u;
                unsigned c8 = (g - o * 640u) * 8u;
                dst = Wcat + (size_t)o * KCAT + c8;
                if (c8 < DIN) {
                    src = bw + (size_t)o * DIN + c8;
                } else {
                    unsigned cc2 = c8 - DIN;
                    unsigned e = cc2 >> 6, r = cc2 & 63u;
                    src = Bm + ((size_t)e * DOUT + o) * RANK + r;
                }
            } else {
                unsigned g2 = g - NG1;
                unsigned row = g2 >> 9;
                unsigned c8  = (g2 & 511u) * 8u;
                dst = W1A + (size_t)row * DIN + c8;
                src = Am + (size_t)row * DIN + c8;
            }
            float4 v0 = *(const float4*)(src);
            float4 v1 = *(const float4*)(src + 4);
            uint4 pk;
            pk.x = (unsigned)f2bf(v0.x) | ((unsigned)f2bf(v0.y) << 16);
            pk.y = (unsigned)f2bf(v0.z) | ((unsigned)f2bf(v0.w) << 16);
            pk.z = (unsigned)f2bf(v1.x) | ((unsigned)f2bf(v1.y) << 16);
            pk.w = (unsigned)f2bf(v1.z) | ((unsigned)f2bf(v1.w) << 16);
            *(uint4*)dst = pk;
        }
    }
}

// ---------- kernel 2: h = Xhi @ A^T (MFMA) + softmax/top2 -> H16 ----------
// 512 blocks x 16 tokens, BK=128: 32 K-iters, 2 blocks/CU for latency overlap.
__global__ void __launch_bounds__(256) proj_moe_kernel(
        const unsigned short* __restrict__ Xcat,
        const unsigned short* __restrict__ W1A,
        const float* __restrict__ Lg, unsigned short* __restrict__ XcatW) {
    __shared__ __align__(16) unsigned short Xs[16 * 128];   // 4 KB
    __shared__ __align__(16) unsigned short Ws[64 * 128];   // 16 KB
    __shared__ __align__(16) float cw[16][16];
    __shared__ __align__(16) float hbuf[16][68];
    const int tid = threadIdx.x;
    const int wave = tid >> 6, lane = tid & 63;
    const int quad = lane >> 4, l16 = lane & 15;
    const int t0 = blockIdx.x * 16;

    // staging maps (LDS slot s = linear thread/instr index; 16-chunk rows)
    const int rX = tid >> 4, cXs = tid & 15;
    const int cX = (cXs & 8) | ((cXs ^ rX) & 7);

    if (tid < 16) {
        float l[16];
        #pragma unroll
        for (int e = 0; e < 16; ++e) l[e] = Lg[(size_t)(t0 + tid) * NEXP + e];
        int i1 = 0; float b1v = l[0];
        #pragma unroll
        for (int e = 1; e < 16; ++e) if (l[e] > b1v) { b1v = l[e]; i1 = e; }
        int i2 = -1; float b2v = -1e30f;
        #pragma unroll
        for (int e = 0; e < 16; ++e) if (e != i1 && l[e] > b2v) { b2v = l[e]; i2 = e; }
        float S = 0.f;
        #pragma unroll
        for (int e = 0; e < 16; ++e) S += expf(l[e] - b1v);
        const float p1 = 1.0f / S;
        const float p2 = expf(b2v - b1v) / S;
        const float d = p1 + p2 + 1e-6f;
        const float c1 = 0.5f * p1 / d;
        const float c2 = 0.5f * p2 / d;
        #pragma unroll
        for (int e = 0; e < 16; ++e)
            cw[tid][e] = (e == i1) ? c1 : (e == i2) ? c2 : 0.0f;
    }

    f32x4 acc = {};
    for (int kt = 0; kt < DIN / 128; ++kt) {
        const int k0 = kt * 128;
        async_cp16(Xcat + (size_t)(t0 + rX) * KCAT + k0 + cX * 8,
                   (char*)Xs + wave * 1024);
        #pragma unroll
        for (int i = 0; i < 4; ++i) {
            const int s = i * 256 + tid;
            const int rW = s >> 4, cWs = s & 15;
            const int cWc = (cWs & 8) | ((cWs ^ rW) & 7);
            async_cp16(W1A + (size_t)rW * DIN + k0 + cWc * 8,
                       (char*)Ws + i * 4096 + wave * 1024);
        }
        __syncthreads();
        #pragma unroll
        for (int kk = 0; kk < 4; ++kk) {
            const int c = kk * 4 + quad;
            const int sa = ((c & 8) | ((c ^ l16) & 7)) << 3;
            const int rb = wave * 16 + l16;
            const int sb = ((c & 8) | ((c ^ rb) & 7)) << 3;
            short8 am = *(const short8*)&Xs[l16 * 128 + sa];
            short8 bn = *(const short8*)&Ws[rb * 128 + sb];
            acc = __builtin_amdgcn_mfma_f32_16x16x32_bf16(am, bn, acc, 0, 0, 0);
        }
        __syncthreads();
    }
    #pragma unroll
    for (int r = 0; r < 4; ++r)
        hbuf[quad * 4 + r][wave * 16 + l16] = acc[r];
    __syncthreads();
    const int t = tid >> 4, e = tid & 15;
    const float c = cw[t][e];
    unsigned short* dst = XcatW + (size_t)(t0 + t) * KCAT + DIN + e * 64;
    #pragma unroll
    for (int r8 = 0; r8 < 8; ++r8) {
        unsigned short o16[8];
        #pragma unroll
        for (int k = 0; k < 8; ++k)
            o16[k] = f2bf(c * hbuf[t][r8 * 8 + k]);
        uint4 pk;
        pk.x = (unsigned)o16[0] | ((unsigned)o16[1] << 16);
        pk.y = (unsigned)o16[2] | ((unsigned)o16[3] << 16);
        pk.z = (unsigned)o16[4] | ((unsigned)o16[5] << 16);
        pk.w = (unsigned)o16[6] | ((unsigned)o16[7] << 16);
        *(uint4*)(dst + r8 * 8) = pk;
    }
}

// ---------- kernel 3: out = Xcat @ Wcat^T + bias, 32x32x16 MFMA ----------
__global__ void __launch_bounds__(256) gemm_main_kernel(
        const unsigned short* __restrict__ Xcat,
        const unsigned short* __restrict__ Wcat,
        const float* __restrict__ bias, float* __restrict__ out) {
    __shared__ __align__(16) unsigned short Xs[128 * 64];
    __shared__ __align__(16) unsigned short Ws[128 * 64];
    const int tid = threadIdx.x;
    const int wave = tid >> 6, lane = tid & 63;
    const int half = lane >> 5, l32 = lane & 31;
    const int bn0 = blockIdx.x * 128;
    const int bm0 = blockIdx.y * 128;
    const int srow = tid >> 3;
    const int scol = ((tid & 7) ^ (srow & 7)) * 8;
    const unsigned short* gx = Xcat + (size_t)(bm0 + srow) * KCAT + scol;
    const unsigned short* gw = Wcat + (size_t)(bn0 + srow) * KCAT + scol;
    const int wm0 = (wave & 1) * 64;
    const int wn0 = (wave >> 1) * 64;
    f32x16 acc[2][2] = {};
    for (int kt = 0; kt < KCAT / 64; ++kt) {
        const int k0 = kt * 64;
        #pragma unroll
        for (int i = 0; i < 4; ++i) {
            async_cp16(gx + (size_t)(i * 32) * KCAT + k0, (char*)Xs + i * 4096 + wave * 1024);
            async_cp16(gw + (size_t)(i * 32) * KCAT + k0, (char*)Ws + i * 4096 + wave * 1024);
        }
        __syncthreads();
        #pragma unroll
        for (int kk2 = 0; kk2 < 4; ++kk2) {     // K=16 each
            const int c = kk2 * 2 + half;        // chunk 0..7
            short8 am[2], bn[2];
            #pragma unroll
            for (int i = 0; i < 2; ++i) {
                const int r = wm0 + i * 32 + l32;
                am[i] = *(const short8*)&Xs[r * 64 + ((c ^ (r & 7)) << 3)];
            }
            #pragma unroll
            for (int j = 0; j < 2; ++j) {
                const int r = wn0 + j * 32 + l32;
                bn[j] = *(const short8*)&Ws[r * 64 + ((c ^ (r & 7)) << 3)];
            }
            #pragma unroll
            for (int i = 0; i < 2; ++i)
                #pragma unroll
                for (int j = 0; j < 2; ++j)
                    acc[i][j] = __builtin_amdgcn_mfma_f32_32x32x16_bf16(
                        am[i], bn[j], acc[i][j], 0, 0, 0);
        }
        __syncthreads();
    }
    // C/D layout (32x32): col = lane&31, row = (reg&3) + 8*(reg>>2) + 4*(lane>>5)
    #pragma unroll
    for (int j = 0; j < 2; ++j) {
        const int col = bn0 + wn0 + j * 32 + l32;
        const float bj = bias[col];
        #pragma unroll
        for (int i = 0; i < 2; ++i) {
            const int rb = bm0 + wm0 + i * 32 + 4 * half;
            #pragma unroll
            for (int r = 0; r < 16; ++r) {
                const int row = rb + (r & 3) + 8 * (r >> 2);
                out[(size_t)row * DOUT + col] = acc[i][j][r] + bj;
            }
        }
    }
}

// ---------- host ----------
extern "C" void kernel_launch(void* const* d_in, const int* in_sizes, int n_in,
                              void* d_out, int out_size, void* d_ws, size_t ws_size,
                              hipStream_t stream) {
    const float* x  = (const float*)d_in[0];
    const float* bw = (const float*)d_in[1];
    const float* bb = (const float*)d_in[2];
    const float* Am = (const float*)d_in[3];
    const float* Bm = (const float*)d_in[4];
    const float* rw = (const float*)d_in[5];
    float* out = (float*)d_out;
    char* ws = (char*)d_ws;
    unsigned short* Xcat = (unsigned short*)(ws);                 // 8192*5120*2 = 83,886,080
    unsigned short* Wcat = (unsigned short*)(ws + 83886080);      // 4096*5120*2 = 41,943,040
    unsigned short* W1A  = (unsigned short*)(ws + 125829120);     // 64*4096*2   =    524,288
    float* Lg = (float*)(ws + 126353408);                         // 8192*16*4   =    524,288

    hipLaunchKernelGGL(prep_all_kernel, dim3(3072),   dim3(256), 0, stream,
                       x, rw, bw, Bm, Am, Xcat, Wcat, W1A, Lg);
    hipLaunchKernelGGL(proj_moe_kernel, dim3(512),    dim3(256), 0, stream,
                       Xcat, W1A, Lg, Xcat);
    hipLaunchKernelGGL(gemm_main_kernel, dim3(32, 64), dim3(256), 0, stream,
                       Xcat, Wcat, bb, out);
}